// Round 16
// baseline (2171.218 us; speedup 1.0000x reference)
//
#include <hip/hip_runtime.h>

// AUGRU, round 16: phase-offset two-tile recurrence.
//  Pass 1 (xproj): VERBATIM R12 (~56 us).
//  Pass 2 (rec): 32 blocks x 1024 thr = 16 waves = TWO B=16 tiles (A: w0-7,
//     B: w8-15, separate LDS state). B offset one phase: each round pairs
//     A.ph1 || B.ph2 -> per SIMD 4 waves with independent chains -> one
//     group's issue fills the other's latency stalls. 401 rounds, uniform
//     barriers. Per-element arithmetic identical to R15.
// Fallback: proven single-kernel (R2) if ws too small.

#define T_N   200
#define I_DIM 128
#define H_DIM 128
#define NBLK  64
#define TCHUNK 25

typedef float  f32x4  __attribute__((ext_vector_type(4)));
typedef __bf16 bf16x4 __attribute__((ext_vector_type(4)));
typedef __bf16 bf16x8 __attribute__((ext_vector_type(8)));

// preact layout: ((t*NBLK+bblk)*3 + g)*4096 + hidgrp*128 + b*8
#define GATE_BYTES 4096
#define PB_BYTES   (3 * GATE_BYTES)
#define PRE_BYTES  ((size_t)T_N * NBLK * PB_BYTES)   // 157,286,400

// fallback LDS
#define LDA_STRIDE 264
#define LATT_STRIDE 201

__device__ __forceinline__ float fast_sigmoid(float x) {
  float e = __builtin_amdgcn_exp2f(-1.4426950408889634f * x);
  return __builtin_amdgcn_rcpf(1.0f + e);
}
__device__ __forceinline__ float fast_tanh(float x) {
  float e = __builtin_amdgcn_exp2f(2.8853900817779268f * x);
  return 1.0f - 2.0f * __builtin_amdgcn_rcpf(1.0f + e);
}
__device__ __forceinline__ void barrier_lds() {
  asm volatile("s_waitcnt lgkmcnt(0)\n\ts_barrier" ::: "memory");
}
__device__ __forceinline__ bf16x8 pack8(float4 a, float4 b) {
  bf16x8 t;
  t[0] = (__bf16)a.x; t[1] = (__bf16)a.y; t[2] = (__bf16)a.z; t[3] = (__bf16)a.w;
  t[4] = (__bf16)b.x; t[5] = (__bf16)b.y; t[6] = (__bf16)b.z; t[7] = (__bf16)b.w;
  return t;
}
// XOR-swizzled byte offset within a [16 row][256 B] bf16 LDS tile (xproj only)
__device__ __forceinline__ int swz(int row, int bytecol) {
  return row * 256 + (bytecol ^ ((row & 7) << 4));
}

// ---------------------------------------------------------------------------
// Pass 1: x-projections, coop-LDS-staged (VERBATIM R12). 512 blocks, 256 thr.
// ---------------------------------------------------------------------------
__global__ __launch_bounds__(256, 2)
void xproj_kernel(const float* __restrict__ inputs,
                  const float* __restrict__ Wz, const float* __restrict__ bz,
                  const float* __restrict__ Wr, const float* __restrict__ br,
                  const float* __restrict__ Wh, const float* __restrict__ bh,
                  char* __restrict__ pre) {
  __shared__ __align__(16) char lds_x[2 * 4096];

  const int tid  = threadIdx.x;
  const int w    = tid >> 6;
  const int l    = tid & 63;
  const int l15  = l & 15;
  const int lk   = l >> 4;
  const int bblk = blockIdx.x & (NBLK - 1);
  const int t0   = (blockIdx.x >> 6) * TCHUNK;
  const int r0   = bblk * 16;

  const int crow  = tid >> 4;
  const int cslot = tid & 15;
  const float* xsrc = inputs + (size_t)(r0 + crow) * (T_N * I_DIM) + cslot * 8;
  const int cwoff = swz(crow, cslot * 16);

  bf16x8 wb[24];
  f32x4  bias4[6];
  #pragma unroll
  for (int s = 0; s < 6; ++s) {
    int hid0 = w * 32 + (s & 1) * 16;
    const float* Wp; const float* bp;
    if (s < 2)      { Wp = Wz; bp = bz; }
    else if (s < 4) { Wp = Wr; bp = br; }
    else            { Wp = Wh; bp = bh; }
    float4 bv = *(const float4*)&bp[hid0 + lk * 4];
    bias4[s][0] = bv.x; bias4[s][1] = bv.y; bias4[s][2] = bv.z; bias4[s][3] = bv.w;
    const float* Wrow = Wp + (size_t)(hid0 + l15) * 256;
    #pragma unroll
    for (int kt = 0; kt < 4; ++kt) {
      const float* p = Wrow + kt * 32 + lk * 8;
      wb[s * 4 + kt] = pack8(*(const float4*)p, *(const float4*)(p + 4));
    }
  }

  {
    const float* p = xsrc + (size_t)t0 * I_DIM;
    float4 a = *(const float4*)p;
    float4 b = *(const float4*)(p + 4);
    *(bf16x8*)(lds_x + cwoff) = pack8(a, b);
  }
  barrier_lds();

  #pragma unroll 2
  for (int ti = 0; ti < TCHUNK; ++ti) {
    const int t = t0 + ti;
    float4 ra, rb2;
    if (ti + 1 < TCHUNK) {
      const float* p = xsrc + (size_t)(t + 1) * I_DIM;
      ra  = *(const float4*)p;
      rb2 = *(const float4*)(p + 4);
    }

    char* bufc = lds_x + ((ti & 1) ? 4096 : 0);
    bf16x8 xf[4];
    #pragma unroll
    for (int kt = 0; kt < 4; ++kt)
      xf[kt] = *(const bf16x8*)(bufc + swz(l15, kt * 64 + lk * 16));

    f32x4 acc[6];
    #pragma unroll
    for (int s = 0; s < 6; ++s) acc[s] = bias4[s];
    #pragma unroll
    for (int kt = 0; kt < 4; ++kt)
      #pragma unroll
      for (int s = 0; s < 6; ++s)
        acc[s] = __builtin_amdgcn_mfma_f32_16x16x32_bf16(wb[s * 4 + kt], xf[kt], acc[s], 0, 0, 0);

    char* base = pre + ((size_t)t * NBLK + bblk) * PB_BYTES;
    #pragma unroll
    for (int s = 0; s < 6; ++s) {
      int g      = s >> 1;
      int hidgrp = w * 8 + (s & 1) * 4 + lk;
      bf16x4 v;
      v[0] = (__bf16)acc[s][0]; v[1] = (__bf16)acc[s][1];
      v[2] = (__bf16)acc[s][2]; v[3] = (__bf16)acc[s][3];
      *(bf16x4*)(base + g * GATE_BYTES + hidgrp * 128 + l15 * 8) = v;
    }

    if (ti + 1 < TCHUNK) {
      char* bufn = lds_x + (((ti + 1) & 1) ? 4096 : 0);
      *(bf16x8*)(bufn + cwoff) = pack8(ra, rb2);
    }
    barrier_lds();
  }
}

// ---------------------------------------------------------------------------
// Pass 2: recurrence, 32 blocks x 1024 thr, two phase-offset tiles per block.
// ---------------------------------------------------------------------------
__global__ __launch_bounds__(1024, 1)
void augru_rec_kernel(const char* __restrict__ pre,
                      const float* __restrict__ attn,
                      const float* __restrict__ Wz,
                      const float* __restrict__ Wr,
                      const float* __restrict__ Wh,
                      float* __restrict__ out) {
  __shared__ __align__(16) char  lds_h [2 * 4096];   // frag-major bf16 h, per group
  __shared__ __align__(16) char  lds_rh[2 * 4096];   // frag-major bf16 rh, per group
  __shared__ float lds_att[2 * T_N * 16];            // [group][t][batch]

  const int tid   = threadIdx.x;
  const int w     = tid >> 6;        // 0..15
  const int g     = w >> 3;          // tile group 0 (A) / 1 (B)
  const int w8    = w & 7;
  const int l     = tid & 63;
  const int l15   = l & 15;
  const int lk    = l >> 4;
  const int r0g   = blockIdx.x * 32 + g * 16;
  const int myhid = w8 * 16 + lk * 4;

  char*  lh  = lds_h  + g * 4096;
  char*  lrh = lds_rh + g * 4096;
  float* lat = lds_att + g * (T_N * 16);

  // ---- prologue ----
  for (int idx = tid; idx < 2 * T_N * 16; idx += 1024) {
    int gg  = idx >= T_N * 16;
    int rem = idx - gg * (T_N * 16);
    int t = rem >> 4, b = rem & 15;
    lds_att[idx] = attn[(size_t)(blockIdx.x * 32 + gg * 16 + b) * T_N + t];
  }
  for (int idx = tid * 4; idx < 2 * 4096; idx += 1024 * 4)
    *(float*)(lds_h + idx) = 0.0f;

  // ---- A-frags (k=128..255), rows = hidden w8*16 + l15 ----
  bf16x8 wzH[4], wrH[4], whH[4];
  {
    const float* pz = Wz + (size_t)(w8 * 16 + l15) * 256 + 128;
    const float* pr = Wr + (size_t)(w8 * 16 + l15) * 256 + 128;
    const float* ph = Wh + (size_t)(w8 * 16 + l15) * 256 + 128;
    #pragma unroll
    for (int kt = 0; kt < 4; ++kt) {
      const float* a = pz + kt * 32 + lk * 8;
      wzH[kt] = pack8(*(const float4*)a, *(const float4*)(a + 4));
      const float* b = pr + kt * 32 + lk * 8;
      wrH[kt] = pack8(*(const float4*)b, *(const float4*)(b + 4));
      const float* cc = ph + kt * 32 + lk * 8;
      whH[kt] = pack8(*(const float4*)cc, *(const float4*)(cc + 4));
    }
  }

  float hreg[4];
  #pragma unroll
  for (int q = 0; q < 4; ++q) hreg[q] = 0.0f;

  // ---- preact ring (depth 2), per-group tile ----
  const int bblk_g = blockIdx.x * 2 + g;
  const char* pb = pre + (size_t)bblk_g * PB_BYTES + (w8 * 4 + lk) * 128 + l15 * 8;
  const size_t tstride = (size_t)NBLK * PB_BYTES;
  bf16x4 pf[2][3];
  #pragma unroll
  for (int d = 0; d < 2; ++d)
    #pragma unroll
    for (int gg = 0; gg < 3; ++gg)
      pf[d][gg] = *(const bf16x4*)(pb + d * tstride + gg * GATE_BYTES);
  const char* pnx = pb + 2 * tstride;

  const int rd_base = (lk * 16 + l15) * 16;
  const int wr_off  = (w8 >> 1) * 1024 + ((((w8 & 1) * 2) + (lk >> 1)) * 16 + l15) * 16 + (lk & 1) * 8;

  float zp[4], phv[4];   // persist between phases

  __syncthreads();

// PH1(tt): consume preacts (z,r,h~->phv), prefetch tt+2, 8 MFMA, rh write, zp.
#define PH1(TT, SLOT)                                                          \
  {                                                                            \
    float pzv[4], prv[4];                                                      \
    _Pragma("unroll")                                                          \
    for (int q = 0; q < 4; ++q) {                                              \
      pzv[q] = (float)pf[SLOT][0][q];                                          \
      prv[q] = (float)pf[SLOT][1][q];                                          \
      phv[q] = (float)pf[SLOT][2][q];                                          \
    }                                                                          \
    if ((TT) + 2 < T_N) {                                                      \
      _Pragma("unroll")                                                        \
      for (int gg = 0; gg < 3; ++gg)                                           \
        pf[SLOT][gg] = *(const bf16x4*)(pnx + gg * GATE_BYTES);                \
      pnx += tstride;                                                          \
    }                                                                          \
    bf16x8 hb[4];                                                              \
    _Pragma("unroll")                                                          \
    for (int kt = 0; kt < 4; ++kt)                                             \
      hb[kt] = *(const bf16x8*)(lh + kt * 1024 + rd_base);                     \
    const float av = lat[(TT) * 16 + l15];                                     \
    f32x4 zA, zB, rA, rB;                                                      \
    { f32x4 a; a[0]=pzv[0]; a[1]=pzv[1]; a[2]=pzv[2]; a[3]=pzv[3]; zA = a; }   \
    { f32x4 a; a[0]=prv[0]; a[1]=prv[1]; a[2]=prv[2]; a[3]=prv[3]; rA = a; }   \
    { f32x4 z; z[0]=0.f; z[1]=0.f; z[2]=0.f; z[3]=0.f; zB = z; rB = z; }       \
    zA = __builtin_amdgcn_mfma_f32_16x16x32_bf16(wzH[0], hb[0], zA, 0, 0, 0);  \
    rA = __builtin_amdgcn_mfma_f32_16x16x32_bf16(wrH[0], hb[0], rA, 0, 0, 0);  \
    zB = __builtin_amdgcn_mfma_f32_16x16x32_bf16(wzH[1], hb[1], zB, 0, 0, 0);  \
    rB = __builtin_amdgcn_mfma_f32_16x16x32_bf16(wrH[1], hb[1], rB, 0, 0, 0);  \
    zA = __builtin_amdgcn_mfma_f32_16x16x32_bf16(wzH[2], hb[2], zA, 0, 0, 0);  \
    rA = __builtin_amdgcn_mfma_f32_16x16x32_bf16(wrH[2], hb[2], rA, 0, 0, 0);  \
    zB = __builtin_amdgcn_mfma_f32_16x16x32_bf16(wzH[3], hb[3], zB, 0, 0, 0);  \
    rB = __builtin_amdgcn_mfma_f32_16x16x32_bf16(wrH[3], hb[3], rB, 0, 0, 0);  \
    bf16x4 rhv;                                                                \
    _Pragma("unroll")                                                          \
    for (int q = 0; q < 4; ++q) {                                              \
      float rr = fast_sigmoid(rA[q] + rB[q]);                                  \
      rhv[q] = (__bf16)(rr * hreg[q]);                                         \
    }                                                                          \
    *(bf16x4*)(lrh + wr_off) = rhv;                                            \
    _Pragma("unroll")                                                          \
    for (int q = 0; q < 4; ++q)                                                \
      zp[q] = av * fast_sigmoid(zA[q] + zB[q]);                                \
  }

// PH2: 4 MFMA on rh, tanh, update h, write h.
#define PH2()                                                                  \
  {                                                                            \
    bf16x8 rb[4];                                                              \
    _Pragma("unroll")                                                          \
    for (int kt = 0; kt < 4; ++kt)                                             \
      rb[kt] = *(const bf16x8*)(lrh + kt * 1024 + rd_base);                    \
    f32x4 hA, hB;                                                              \
    { f32x4 a; a[0]=phv[0]; a[1]=phv[1]; a[2]=phv[2]; a[3]=phv[3]; hA = a; }   \
    { f32x4 z; z[0]=0.f; z[1]=0.f; z[2]=0.f; z[3]=0.f; hB = z; }               \
    hA = __builtin_amdgcn_mfma_f32_16x16x32_bf16(whH[0], rb[0], hA, 0, 0, 0);  \
    hB = __builtin_amdgcn_mfma_f32_16x16x32_bf16(whH[1], rb[1], hB, 0, 0, 0);  \
    hA = __builtin_amdgcn_mfma_f32_16x16x32_bf16(whH[2], rb[2], hA, 0, 0, 0);  \
    hB = __builtin_amdgcn_mfma_f32_16x16x32_bf16(whH[3], rb[3], hB, 0, 0, 0);  \
    bf16x4 hbv;                                                                \
    _Pragma("unroll")                                                          \
    for (int q = 0; q < 4; ++q) {                                              \
      float ht = fast_tanh(hA[q] + hB[q]);                                     \
      float hn = __builtin_fmaf(zp[q], ht - hreg[q], hreg[q]);                 \
      hreg[q] = hn;                                                            \
      hbv[q] = (__bf16)hn;                                                     \
    }                                                                          \
    *(bf16x4*)(lh + wr_off) = hbv;                                             \
  }

  // round 0: A.ph1(0), B idle
  if (g == 0) PH1(0, 0)
  barrier_lds();

  #pragma unroll 2
  for (int t = 0; t < T_N; ++t) {
    // round 2t+1: A.ph2(t) || B.ph1(t)
    if (g == 0) PH2()
    else        PH1(t, (t & 1))
    barrier_lds();
    // round 2t+2: A.ph1(t+1) || B.ph2(t)
    if (g == 0) { if (t + 1 < T_N) PH1(t + 1, ((t + 1) & 1)) }
    else        PH2()
    if (t + 1 < T_N) barrier_lds();
  }
#undef PH1
#undef PH2

  float4 o;
  o.x = hreg[0]; o.y = hreg[1]; o.z = hreg[2]; o.w = hreg[3];
  *(float4*)&out[(size_t)(r0g + l15) * H_DIM + myhid] = o;
}

// ---------------------------------------------------------------------------
// Fallback: proven single-kernel version (round 2, 410 us).
// ---------------------------------------------------------------------------
__global__ __launch_bounds__(256, 1)
void augru_kernel(const float* __restrict__ inputs,
                  const float* __restrict__ attn,
                  const float* __restrict__ Wz, const float* __restrict__ bz,
                  const float* __restrict__ Wr, const float* __restrict__ br,
                  const float* __restrict__ Wh, const float* __restrict__ bh,
                  float* __restrict__ out) {
  __shared__ __align__(16) short lds_a[16 * LDA_STRIDE];
  __shared__ float lds_att[16 * LATT_STRIDE];

  const int tid = threadIdx.x;
  const int w   = tid >> 6;
  const int l   = tid & 63;
  const int l15 = l & 15;
  const int lk  = l >> 4;
  const int r0  = blockIdx.x * 16;

  for (int idx = tid; idx < 16 * T_N; idx += 256) {
    int row = idx / T_N, t = idx - row * T_N;
    lds_att[row * LATT_STRIDE + t] = attn[(size_t)(r0 + row) * T_N + t];
  }
  for (int idx = tid; idx < 16 * H_DIM; idx += 256) {
    int row = idx >> 7, c = idx & 127;
    lds_a[row * LDA_STRIDE + c] = 0;
  }

  bf16x8 w1[32];
  float  bias1[4];
  #pragma unroll
  for (int ct = 0; ct < 4; ++ct) {
    int n = w * 32 + (ct & 1) * 16 + l15;
    const float* Wp; float bv;
    if (ct < 2) { Wp = Wz + (size_t)n * 256; bv = bz[n]; }
    else        { Wp = Wr + (size_t)n * 256; bv = br[n]; }
    bias1[ct] = bv;
    #pragma unroll
    for (int kt = 0; kt < 8; ++kt) {
      const float* p = Wp + kt * 32 + lk * 8;
      w1[ct * 8 + kt] = pack8(*(const float4*)p, *(const float4*)(p + 4));
    }
  }
  bf16x8 w2[16];
  float  bias2[2];
  #pragma unroll
  for (int ct = 0; ct < 2; ++ct) {
    int n = w * 32 + ct * 16 + l15;
    bias2[ct] = bh[n];
    const float* Wp = Wh + (size_t)n * 256;
    #pragma unroll
    for (int kt = 0; kt < 8; ++kt) {
      const float* p = Wp + kt * 32 + lk * 8;
      w2[ct * 8 + kt] = pack8(*(const float4*)p, *(const float4*)(p + 4));
    }
  }

  float hreg[2][4];
  #pragma unroll
  for (int ct = 0; ct < 2; ++ct)
    #pragma unroll
    for (int q = 0; q < 4; ++q) hreg[ct][q] = 0.0f;

  const float* xbase = inputs + (size_t)(r0 + l15) * (T_N * I_DIM);
  bf16x8 xfrag[4];
  #pragma unroll
  for (int kt = 0; kt < 4; ++kt) {
    const float* p = xbase + kt * 32 + lk * 8;
    xfrag[kt] = pack8(*(const float4*)p, *(const float4*)(p + 4));
  }

  __syncthreads();

  float4 xr0[4], xr1[4];
  for (int t = 0; t < T_N; ++t) {
    if (t + 1 < T_N) {
      #pragma unroll
      for (int kt = 0; kt < 4; ++kt) {
        const float* p = xbase + (size_t)(t + 1) * I_DIM + kt * 32 + lk * 8;
        xr0[kt] = *(const float4*)p;
        xr1[kt] = *(const float4*)(p + 4);
      }
    }
    bf16x8 hfrag[4];
    #pragma unroll
    for (int kt = 0; kt < 4; ++kt)
      hfrag[kt] = *(const bf16x8*)&lds_a[l15 * LDA_STRIDE + kt * 32 + lk * 8];
    float av[4];
    #pragma unroll
    for (int q = 0; q < 4; ++q) av[q] = lds_att[(lk * 4 + q) * LATT_STRIDE + t];

    f32x4 acc[4];
    #pragma unroll
    for (int ct = 0; ct < 4; ++ct) {
      f32x4 a; a[0] = bias1[ct]; a[1] = bias1[ct]; a[2] = bias1[ct]; a[3] = bias1[ct];
      acc[ct] = a;
    }
    #pragma unroll
    for (int kt = 0; kt < 4; ++kt)
      #pragma unroll
      for (int ct = 0; ct < 4; ++ct)
        acc[ct] = __builtin_amdgcn_mfma_f32_16x16x32_bf16(xfrag[kt], w1[ct * 8 + kt], acc[ct], 0, 0, 0);

    f32x4 acc2[2];
    #pragma unroll
    for (int ct = 0; ct < 2; ++ct) {
      f32x4 a; a[0] = bias2[ct]; a[1] = bias2[ct]; a[2] = bias2[ct]; a[3] = bias2[ct];
      acc2[ct] = a;
    }
    #pragma unroll
    for (int kt = 0; kt < 4; ++kt)
      #pragma unroll
      for (int ct = 0; ct < 2; ++ct)
        acc2[ct] = __builtin_amdgcn_mfma_f32_16x16x32_bf16(xfrag[kt], w2[ct * 8 + kt], acc2[ct], 0, 0, 0);

    #pragma unroll
    for (int kt = 0; kt < 4; ++kt)
      #pragma unroll
      for (int ct = 0; ct < 4; ++ct)
        acc[ct] = __builtin_amdgcn_mfma_f32_16x16x32_bf16(hfrag[kt], w1[ct * 8 + 4 + kt], acc[ct], 0, 0, 0);

    float zp[2][4];
    #pragma unroll
    for (int ct = 0; ct < 2; ++ct) {
      int col = w * 32 + ct * 16 + l15;
      #pragma unroll
      for (int q = 0; q < 4; ++q) {
        int row = lk * 4 + q;
        zp[ct][q] = av[q] * fast_sigmoid(acc[ct][q]);
        float rr = fast_sigmoid(acc[2 + ct][q]);
        __bf16 rhb = (__bf16)(rr * hreg[ct][q]);
        lds_a[row * LDA_STRIDE + 128 + col] = __builtin_bit_cast(short, rhb);
      }
    }
    barrier_lds();

    bf16x8 rfrag[4];
    #pragma unroll
    for (int kt = 0; kt < 4; ++kt)
      rfrag[kt] = *(const bf16x8*)&lds_a[l15 * LDA_STRIDE + 128 + kt * 32 + lk * 8];
    #pragma unroll
    for (int kt = 0; kt < 4; ++kt)
      #pragma unroll
      for (int ct = 0; ct < 2; ++ct)
        acc2[ct] = __builtin_amdgcn_mfma_f32_16x16x32_bf16(rfrag[kt], w2[ct * 8 + 4 + kt], acc2[ct], 0, 0, 0);

    if (t + 1 < T_N) {
      #pragma unroll
      for (int kt = 0; kt < 4; ++kt)
        xfrag[kt] = pack8(xr0[kt], xr1[kt]);
    }

    #pragma unroll
    for (int ct = 0; ct < 2; ++ct) {
      int col = w * 32 + ct * 16 + l15;
      #pragma unroll
      for (int q = 0; q < 4; ++q) {
        int row = lk * 4 + q;
        float ht = fast_tanh(acc2[ct][q]);
        float ho = hreg[ct][q];
        float hn = __builtin_fmaf(zp[ct][q], ht - ho, ho);
        hreg[ct][q] = hn;
        __bf16 hb = (__bf16)hn;
        lds_a[row * LDA_STRIDE + col] = __builtin_bit_cast(short, hb);
      }
    }
    barrier_lds();
  }

  #pragma unroll
  for (int ct = 0; ct < 2; ++ct) {
    int col = w * 32 + ct * 16 + l15;
    #pragma unroll
    for (int q = 0; q < 4; ++q) {
      int row = lk * 4 + q;
      out[(size_t)(r0 + row) * H_DIM + col] = hreg[ct][q];
    }
  }
}

extern "C" void kernel_launch(void* const* d_in, const int* in_sizes, int n_in,
                              void* d_out, int out_size, void* d_ws, size_t ws_size,
                              hipStream_t stream) {
  (void)in_sizes; (void)n_in; (void)out_size;
  const float* inputs = (const float*)d_in[0];
  const float* attn   = (const float*)d_in[1];
  const float* Wz     = (const float*)d_in[2];
  const float* bz     = (const float*)d_in[3];
  const float* Wr     = (const float*)d_in[4];
  const float* br     = (const float*)d_in[5];
  const float* Wh     = (const float*)d_in[6];
  const float* bh     = (const float*)d_in[7];
  float* out = (float*)d_out;

  if (ws_size >= PRE_BYTES) {
    char* pre = (char*)d_ws;
    xproj_kernel<<<NBLK * (T_N / TCHUNK), 256, 0, stream>>>(inputs, Wz, bz, Wr, br, Wh, bh, pre);
    augru_rec_kernel<<<32, 1024, 0, stream>>>(pre, attn, Wz, Wr, Wh, out);
  } else {
    augru_kernel<<<NBLK, 256, 0, stream>>>(inputs, attn, Wz, bz, Wr, br, Wh, bh, out);
  }
}

// Round 17
// 439.513 us; speedup vs baseline: 4.9401x; 4.9401x over previous
//
#include <hip/hip_runtime.h>

// AUGRU, round 17: phase-offset two-tile recurrence, fixed compilation.
//  R16's failure was implementation, not mechanism: (a) pf[t&1] via macro ->
//  scratch (WRITE_SIZE 512->2176KB); (b) per-lane group branch -> exec-masked
//  dual execution. Fixes: scalar-uniform branch via readfirstlane; named
//  pfE/pfO slots with literal indices; 4 explicit rounds per tt+=2.
//  Pass 1 (xproj): VERBATIM R12 (~56 us).
//  Pass 2 (rec): 32 blocks x 1024 thr = two B=16 tiles (A: tid<512, B: rest),
//     B offset one phase -> 4 independent dep-chains per SIMD.
// Fallback: proven single-kernel (R2) if ws too small.

#define T_N   200
#define I_DIM 128
#define H_DIM 128
#define NBLK  64
#define TCHUNK 25

typedef float  f32x4  __attribute__((ext_vector_type(4)));
typedef __bf16 bf16x4 __attribute__((ext_vector_type(4)));
typedef __bf16 bf16x8 __attribute__((ext_vector_type(8)));

// preact layout: ((t*NBLK+bblk)*3 + g)*4096 + hidgrp*128 + b*8
#define GATE_BYTES 4096
#define PB_BYTES   (3 * GATE_BYTES)
#define PRE_BYTES  ((size_t)T_N * NBLK * PB_BYTES)   // 157,286,400

// fallback LDS
#define LDA_STRIDE 264
#define LATT_STRIDE 201

__device__ __forceinline__ float fast_sigmoid(float x) {
  float e = __builtin_amdgcn_exp2f(-1.4426950408889634f * x);
  return __builtin_amdgcn_rcpf(1.0f + e);
}
__device__ __forceinline__ float fast_tanh(float x) {
  float e = __builtin_amdgcn_exp2f(2.8853900817779268f * x);
  return 1.0f - 2.0f * __builtin_amdgcn_rcpf(1.0f + e);
}
__device__ __forceinline__ void barrier_lds() {
  asm volatile("s_waitcnt lgkmcnt(0)\n\ts_barrier" ::: "memory");
}
__device__ __forceinline__ bf16x8 pack8(float4 a, float4 b) {
  bf16x8 t;
  t[0] = (__bf16)a.x; t[1] = (__bf16)a.y; t[2] = (__bf16)a.z; t[3] = (__bf16)a.w;
  t[4] = (__bf16)b.x; t[5] = (__bf16)b.y; t[6] = (__bf16)b.z; t[7] = (__bf16)b.w;
  return t;
}
// XOR-swizzled byte offset within a [16 row][256 B] bf16 LDS tile (xproj only)
__device__ __forceinline__ int swz(int row, int bytecol) {
  return row * 256 + (bytecol ^ ((row & 7) << 4));
}

// ---------------------------------------------------------------------------
// Pass 1: x-projections, coop-LDS-staged (VERBATIM R12). 512 blocks, 256 thr.
// ---------------------------------------------------------------------------
__global__ __launch_bounds__(256, 2)
void xproj_kernel(const float* __restrict__ inputs,
                  const float* __restrict__ Wz, const float* __restrict__ bz,
                  const float* __restrict__ Wr, const float* __restrict__ br,
                  const float* __restrict__ Wh, const float* __restrict__ bh,
                  char* __restrict__ pre) {
  __shared__ __align__(16) char lds_x[2 * 4096];

  const int tid  = threadIdx.x;
  const int w    = tid >> 6;
  const int l    = tid & 63;
  const int l15  = l & 15;
  const int lk   = l >> 4;
  const int bblk = blockIdx.x & (NBLK - 1);
  const int t0   = (blockIdx.x >> 6) * TCHUNK;
  const int r0   = bblk * 16;

  const int crow  = tid >> 4;
  const int cslot = tid & 15;
  const float* xsrc = inputs + (size_t)(r0 + crow) * (T_N * I_DIM) + cslot * 8;
  const int cwoff = swz(crow, cslot * 16);

  bf16x8 wb[24];
  f32x4  bias4[6];
  #pragma unroll
  for (int s = 0; s < 6; ++s) {
    int hid0 = w * 32 + (s & 1) * 16;
    const float* Wp; const float* bp;
    if (s < 2)      { Wp = Wz; bp = bz; }
    else if (s < 4) { Wp = Wr; bp = br; }
    else            { Wp = Wh; bp = bh; }
    float4 bv = *(const float4*)&bp[hid0 + lk * 4];
    bias4[s][0] = bv.x; bias4[s][1] = bv.y; bias4[s][2] = bv.z; bias4[s][3] = bv.w;
    const float* Wrow = Wp + (size_t)(hid0 + l15) * 256;
    #pragma unroll
    for (int kt = 0; kt < 4; ++kt) {
      const float* p = Wrow + kt * 32 + lk * 8;
      wb[s * 4 + kt] = pack8(*(const float4*)p, *(const float4*)(p + 4));
    }
  }

  {
    const float* p = xsrc + (size_t)t0 * I_DIM;
    float4 a = *(const float4*)p;
    float4 b = *(const float4*)(p + 4);
    *(bf16x8*)(lds_x + cwoff) = pack8(a, b);
  }
  barrier_lds();

  #pragma unroll 2
  for (int ti = 0; ti < TCHUNK; ++ti) {
    const int t = t0 + ti;
    float4 ra, rb2;
    if (ti + 1 < TCHUNK) {
      const float* p = xsrc + (size_t)(t + 1) * I_DIM;
      ra  = *(const float4*)p;
      rb2 = *(const float4*)(p + 4);
    }

    char* bufc = lds_x + ((ti & 1) ? 4096 : 0);
    bf16x8 xf[4];
    #pragma unroll
    for (int kt = 0; kt < 4; ++kt)
      xf[kt] = *(const bf16x8*)(bufc + swz(l15, kt * 64 + lk * 16));

    f32x4 acc[6];
    #pragma unroll
    for (int s = 0; s < 6; ++s) acc[s] = bias4[s];
    #pragma unroll
    for (int kt = 0; kt < 4; ++kt)
      #pragma unroll
      for (int s = 0; s < 6; ++s)
        acc[s] = __builtin_amdgcn_mfma_f32_16x16x32_bf16(wb[s * 4 + kt], xf[kt], acc[s], 0, 0, 0);

    char* base = pre + ((size_t)t * NBLK + bblk) * PB_BYTES;
    #pragma unroll
    for (int s = 0; s < 6; ++s) {
      int g      = s >> 1;
      int hidgrp = w * 8 + (s & 1) * 4 + lk;
      bf16x4 v;
      v[0] = (__bf16)acc[s][0]; v[1] = (__bf16)acc[s][1];
      v[2] = (__bf16)acc[s][2]; v[3] = (__bf16)acc[s][3];
      *(bf16x4*)(base + g * GATE_BYTES + hidgrp * 128 + l15 * 8) = v;
    }

    if (ti + 1 < TCHUNK) {
      char* bufn = lds_x + (((ti + 1) & 1) ? 4096 : 0);
      *(bf16x8*)(bufn + cwoff) = pack8(ra, rb2);
    }
    barrier_lds();
  }
}

// ---------------------------------------------------------------------------
// Pass 2: recurrence, 32 blocks x 1024 thr, two phase-offset tiles per block.
// ---------------------------------------------------------------------------
__global__ __launch_bounds__(1024, 1)
void augru_rec_kernel(const char* __restrict__ pre,
                      const float* __restrict__ attn,
                      const float* __restrict__ Wz,
                      const float* __restrict__ Wr,
                      const float* __restrict__ Wh,
                      float* __restrict__ out) {
  __shared__ __align__(16) char  lds_h [2 * 4096];   // frag-major bf16 h, per group
  __shared__ __align__(16) char  lds_rh[2 * 4096];   // frag-major bf16 rh, per group
  __shared__ float lds_att[2 * T_N * 16];            // [group][t][batch]

  const int tid = threadIdx.x;
  const int w   = tid >> 6;          // 0..15
  const int gd  = w >> 3;            // group (wave-uniform value, per-lane reg)
  const int w8  = w & 7;
  const int l15 = tid & 15;
  const int lk  = (tid >> 4) & 3;
  // scalar-uniform group flag -> true s_cbranch, no predication
  const bool isA = (__builtin_amdgcn_readfirstlane(tid) & 512) == 0;

  char*  lh  = lds_h  + gd * 4096;
  char*  lrh = lds_rh + gd * 4096;
  float* lat = lds_att + gd * (T_N * 16);

  // ---- prologue ----
  for (int idx = tid; idx < 2 * T_N * 16; idx += 1024) {
    int gg  = idx >= T_N * 16;
    int rem = idx - gg * (T_N * 16);
    int t = rem >> 4, b = rem & 15;
    lds_att[idx] = attn[(size_t)(blockIdx.x * 32 + gg * 16 + b) * T_N + t];
  }
  for (int idx = tid * 4; idx < 2 * 4096; idx += 1024 * 4)
    *(float*)(lds_h + idx) = 0.0f;

  // ---- A-frags (k=128..255), rows = hidden w8*16 + l15 ----
  bf16x8 wzH[4], wrH[4], whH[4];
  {
    const float* pz = Wz + (size_t)(w8 * 16 + l15) * 256 + 128;
    const float* pr = Wr + (size_t)(w8 * 16 + l15) * 256 + 128;
    const float* ph = Wh + (size_t)(w8 * 16 + l15) * 256 + 128;
    #pragma unroll
    for (int kt = 0; kt < 4; ++kt) {
      const float* a = pz + kt * 32 + lk * 8;
      wzH[kt] = pack8(*(const float4*)a, *(const float4*)(a + 4));
      const float* b = pr + kt * 32 + lk * 8;
      wrH[kt] = pack8(*(const float4*)b, *(const float4*)(b + 4));
      const float* cc = ph + kt * 32 + lk * 8;
      whH[kt] = pack8(*(const float4*)cc, *(const float4*)(cc + 4));
    }
  }

  float hreg[4];
  #pragma unroll
  for (int q = 0; q < 4; ++q) hreg[q] = 0.0f;

  // ---- preact ring: named even/odd slots, literal indices only ----
  const int bblk_g = blockIdx.x * 2 + gd;
  const char* pb = pre + (size_t)bblk_g * PB_BYTES + (w8 * 4 + lk) * 128 + l15 * 8;
  const size_t tstride = (size_t)NBLK * PB_BYTES;
  bf16x4 pfE[3], pfO[3];
  #pragma unroll
  for (int gg = 0; gg < 3; ++gg) {
    pfE[gg] = *(const bf16x4*)(pb + gg * GATE_BYTES);                // t=0
    pfO[gg] = *(const bf16x4*)(pb + tstride + gg * GATE_BYTES);      // t=1
  }

  const int rd_base = (lk * 16 + l15) * 16;
  const int wr_off  = (w8 >> 1) * 1024 + ((((w8 & 1) * 2) + (lk >> 1)) * 16 + l15) * 16 + (lk & 1) * 8;

  float zp[4], phv[4];   // live between a wave's PH1 and its PH2

  __syncthreads();

// PH1(TT, PF): consume preacts from PF, prefetch TT+2 into PF, 8 MFMA,
//              rh -> LDS, zp in regs.
#define PH1(TT, PF)                                                            \
  {                                                                            \
    float pzv[4], prv[4];                                                      \
    _Pragma("unroll")                                                          \
    for (int q = 0; q < 4; ++q) {                                              \
      pzv[q] = (float)PF[0][q];                                                \
      prv[q] = (float)PF[1][q];                                                \
      phv[q] = (float)PF[2][q];                                                \
    }                                                                          \
    if ((TT) + 2 < T_N) {                                                      \
      const char* bptr = pb + (size_t)((TT) + 2) * tstride;                    \
      _Pragma("unroll")                                                        \
      for (int gg = 0; gg < 3; ++gg)                                           \
        PF[gg] = *(const bf16x4*)(bptr + gg * GATE_BYTES);                     \
    }                                                                          \
    bf16x8 hb[4];                                                              \
    _Pragma("unroll")                                                          \
    for (int kt = 0; kt < 4; ++kt)                                             \
      hb[kt] = *(const bf16x8*)(lh + kt * 1024 + rd_base);                     \
    const float av = lat[(TT) * 16 + l15];                                     \
    f32x4 zA, zB, rA, rB;                                                      \
    { f32x4 a; a[0]=pzv[0]; a[1]=pzv[1]; a[2]=pzv[2]; a[3]=pzv[3]; zA = a; }   \
    { f32x4 a; a[0]=prv[0]; a[1]=prv[1]; a[2]=prv[2]; a[3]=prv[3]; rA = a; }   \
    { f32x4 z; z[0]=0.f; z[1]=0.f; z[2]=0.f; z[3]=0.f; zB = z; rB = z; }       \
    zA = __builtin_amdgcn_mfma_f32_16x16x32_bf16(wzH[0], hb[0], zA, 0, 0, 0);  \
    rA = __builtin_amdgcn_mfma_f32_16x16x32_bf16(wrH[0], hb[0], rA, 0, 0, 0);  \
    zB = __builtin_amdgcn_mfma_f32_16x16x32_bf16(wzH[1], hb[1], zB, 0, 0, 0);  \
    rB = __builtin_amdgcn_mfma_f32_16x16x32_bf16(wrH[1], hb[1], rB, 0, 0, 0);  \
    zA = __builtin_amdgcn_mfma_f32_16x16x32_bf16(wzH[2], hb[2], zA, 0, 0, 0);  \
    rA = __builtin_amdgcn_mfma_f32_16x16x32_bf16(wrH[2], hb[2], rA, 0, 0, 0);  \
    zB = __builtin_amdgcn_mfma_f32_16x16x32_bf16(wzH[3], hb[3], zB, 0, 0, 0);  \
    rB = __builtin_amdgcn_mfma_f32_16x16x32_bf16(wrH[3], hb[3], rB, 0, 0, 0);  \
    bf16x4 rhv;                                                                \
    _Pragma("unroll")                                                          \
    for (int q = 0; q < 4; ++q) {                                              \
      float rr = fast_sigmoid(rA[q] + rB[q]);                                  \
      rhv[q] = (__bf16)(rr * hreg[q]);                                         \
    }                                                                          \
    *(bf16x4*)(lrh + wr_off) = rhv;                                            \
    _Pragma("unroll")                                                          \
    for (int q = 0; q < 4; ++q)                                                \
      zp[q] = av * fast_sigmoid(zA[q] + zB[q]);                                \
  }

// PH2: 4 MFMA on rh, tanh, update h, write h.
#define PH2()                                                                  \
  {                                                                            \
    bf16x8 rb[4];                                                              \
    _Pragma("unroll")                                                          \
    for (int kt = 0; kt < 4; ++kt)                                             \
      rb[kt] = *(const bf16x8*)(lrh + kt * 1024 + rd_base);                    \
    f32x4 hA, hB;                                                              \
    { f32x4 a; a[0]=phv[0]; a[1]=phv[1]; a[2]=phv[2]; a[3]=phv[3]; hA = a; }   \
    { f32x4 z; z[0]=0.f; z[1]=0.f; z[2]=0.f; z[3]=0.f; hB = z; }               \
    hA = __builtin_amdgcn_mfma_f32_16x16x32_bf16(whH[0], rb[0], hA, 0, 0, 0);  \
    hB = __builtin_amdgcn_mfma_f32_16x16x32_bf16(whH[1], rb[1], hB, 0, 0, 0);  \
    hA = __builtin_amdgcn_mfma_f32_16x16x32_bf16(whH[2], rb[2], hA, 0, 0, 0);  \
    hB = __builtin_amdgcn_mfma_f32_16x16x32_bf16(whH[3], rb[3], hB, 0, 0, 0);  \
    bf16x4 hbv;                                                                \
    _Pragma("unroll")                                                          \
    for (int q = 0; q < 4; ++q) {                                              \
      float ht = fast_tanh(hA[q] + hB[q]);                                     \
      float hn = __builtin_fmaf(zp[q], ht - hreg[q], hreg[q]);                 \
      hreg[q] = hn;                                                            \
      hbv[q] = (__bf16)hn;                                                     \
    }                                                                          \
    *(bf16x4*)(lh + wr_off) = hbv;                                             \
  }

  // round 0: A.ph1(0) [E]; B idle
  if (isA) PH1(0, pfE)
  barrier_lds();

  for (int tt = 0; tt < T_N; tt += 2) {
    // round: A.ph2(tt) || B.ph1(tt) [E]
    if (isA) PH2()
    else     PH1(tt, pfE)
    barrier_lds();
    // round: A.ph1(tt+1) [O] || B.ph2(tt)
    if (isA) PH1(tt + 1, pfO)
    else     PH2()
    barrier_lds();
    // round: A.ph2(tt+1) || B.ph1(tt+1) [O]
    if (isA) PH2()
    else     PH1(tt + 1, pfO)
    barrier_lds();
    // round: A.ph1(tt+2) [E] (guarded) || B.ph2(tt+1)
    if (isA) { if (tt + 2 < T_N) PH1(tt + 2, pfE) }
    else     PH2()
    barrier_lds();
  }
#undef PH1
#undef PH2

  const int r0g   = blockIdx.x * 32 + gd * 16;
  const int myhid = w8 * 16 + lk * 4;
  float4 o;
  o.x = hreg[0]; o.y = hreg[1]; o.z = hreg[2]; o.w = hreg[3];
  *(float4*)&out[(size_t)(r0g + l15) * H_DIM + myhid] = o;
}

// ---------------------------------------------------------------------------
// Fallback: proven single-kernel version (round 2, 410 us).
// ---------------------------------------------------------------------------
__global__ __launch_bounds__(256, 1)
void augru_kernel(const float* __restrict__ inputs,
                  const float* __restrict__ attn,
                  const float* __restrict__ Wz, const float* __restrict__ bz,
                  const float* __restrict__ Wr, const float* __restrict__ br,
                  const float* __restrict__ Wh, const float* __restrict__ bh,
                  float* __restrict__ out) {
  __shared__ __align__(16) short lds_a[16 * LDA_STRIDE];
  __shared__ float lds_att[16 * LATT_STRIDE];

  const int tid = threadIdx.x;
  const int w   = tid >> 6;
  const int l   = tid & 63;
  const int l15 = l & 15;
  const int lk  = l >> 4;
  const int r0  = blockIdx.x * 16;

  for (int idx = tid; idx < 16 * T_N; idx += 256) {
    int row = idx / T_N, t = idx - row * T_N;
    lds_att[row * LATT_STRIDE + t] = attn[(size_t)(r0 + row) * T_N + t];
  }
  for (int idx = tid; idx < 16 * H_DIM; idx += 256) {
    int row = idx >> 7, c = idx & 127;
    lds_a[row * LDA_STRIDE + c] = 0;
  }

  bf16x8 w1[32];
  float  bias1[4];
  #pragma unroll
  for (int ct = 0; ct < 4; ++ct) {
    int n = w * 32 + (ct & 1) * 16 + l15;
    const float* Wp; float bv;
    if (ct < 2) { Wp = Wz + (size_t)n * 256; bv = bz[n]; }
    else        { Wp = Wr + (size_t)n * 256; bv = br[n]; }
    bias1[ct] = bv;
    #pragma unroll
    for (int kt = 0; kt < 8; ++kt) {
      const float* p = Wp + kt * 32 + lk * 8;
      w1[ct * 8 + kt] = pack8(*(const float4*)p, *(const float4*)(p + 4));
    }
  }
  bf16x8 w2[16];
  float  bias2[2];
  #pragma unroll
  for (int ct = 0; ct < 2; ++ct) {
    int n = w * 32 + ct * 16 + l15;
    bias2[ct] = bh[n];
    const float* Wp = Wh + (size_t)n * 256;
    #pragma unroll
    for (int kt = 0; kt < 8; ++kt) {
      const float* p = Wp + kt * 32 + lk * 8;
      w2[ct * 8 + kt] = pack8(*(const float4*)p, *(const float4*)(p + 4));
    }
  }

  float hreg[2][4];
  #pragma unroll
  for (int ct = 0; ct < 2; ++ct)
    #pragma unroll
    for (int q = 0; q < 4; ++q) hreg[ct][q] = 0.0f;

  const float* xbase = inputs + (size_t)(r0 + l15) * (T_N * I_DIM);
  bf16x8 xfrag[4];
  #pragma unroll
  for (int kt = 0; kt < 4; ++kt) {
    const float* p = xbase + kt * 32 + lk * 8;
    xfrag[kt] = pack8(*(const float4*)p, *(const float4*)(p + 4));
  }

  __syncthreads();

  float4 xr0[4], xr1[4];
  for (int t = 0; t < T_N; ++t) {
    if (t + 1 < T_N) {
      #pragma unroll
      for (int kt = 0; kt < 4; ++kt) {
        const float* p = xbase + (size_t)(t + 1) * I_DIM + kt * 32 + lk * 8;
        xr0[kt] = *(const float4*)p;
        xr1[kt] = *(const float4*)(p + 4);
      }
    }
    bf16x8 hfrag[4];
    #pragma unroll
    for (int kt = 0; kt < 4; ++kt)
      hfrag[kt] = *(const bf16x8*)&lds_a[l15 * LDA_STRIDE + kt * 32 + lk * 8];
    float av[4];
    #pragma unroll
    for (int q = 0; q < 4; ++q) av[q] = lds_att[(lk * 4 + q) * LATT_STRIDE + t];

    f32x4 acc[4];
    #pragma unroll
    for (int ct = 0; ct < 4; ++ct) {
      f32x4 a; a[0] = bias1[ct]; a[1] = bias1[ct]; a[2] = bias1[ct]; a[3] = bias1[ct];
      acc[ct] = a;
    }
    #pragma unroll
    for (int kt = 0; kt < 4; ++kt)
      #pragma unroll
      for (int ct = 0; ct < 4; ++ct)
        acc[ct] = __builtin_amdgcn_mfma_f32_16x16x32_bf16(xfrag[kt], w1[ct * 8 + kt], acc[ct], 0, 0, 0);

    f32x4 acc2[2];
    #pragma unroll
    for (int ct = 0; ct < 2; ++ct) {
      f32x4 a; a[0] = bias2[ct]; a[1] = bias2[ct]; a[2] = bias2[ct]; a[3] = bias2[ct];
      acc2[ct] = a;
    }
    #pragma unroll
    for (int kt = 0; kt < 4; ++kt)
      #pragma unroll
      for (int ct = 0; ct < 2; ++ct)
        acc2[ct] = __builtin_amdgcn_mfma_f32_16x16x32_bf16(xfrag[kt], w2[ct * 8 + kt], acc2[ct], 0, 0, 0);

    #pragma unroll
    for (int kt = 0; kt < 4; ++kt)
      #pragma unroll
      for (int ct = 0; ct < 4; ++ct)
        acc[ct] = __builtin_amdgcn_mfma_f32_16x16x32_bf16(hfrag[kt], w1[ct * 8 + 4 + kt], acc[ct], 0, 0, 0);

    float zp[2][4];
    #pragma unroll
    for (int ct = 0; ct < 2; ++ct) {
      int col = w * 32 + ct * 16 + l15;
      #pragma unroll
      for (int q = 0; q < 4; ++q) {
        int row = lk * 4 + q;
        zp[ct][q] = av[q] * fast_sigmoid(acc[ct][q]);
        float rr = fast_sigmoid(acc[2 + ct][q]);
        __bf16 rhb = (__bf16)(rr * hreg[ct][q]);
        lds_a[row * LDA_STRIDE + 128 + col] = __builtin_bit_cast(short, rhb);
      }
    }
    barrier_lds();

    bf16x8 rfrag[4];
    #pragma unroll
    for (int kt = 0; kt < 4; ++kt)
      rfrag[kt] = *(const bf16x8*)&lds_a[l15 * LDA_STRIDE + 128 + kt * 32 + lk * 8];
    #pragma unroll
    for (int kt = 0; kt < 4; ++kt)
      #pragma unroll
      for (int ct = 0; ct < 2; ++ct)
        acc2[ct] = __builtin_amdgcn_mfma_f32_16x16x32_bf16(rfrag[kt], w2[ct * 8 + 4 + kt], acc2[ct], 0, 0, 0);

    if (t + 1 < T_N) {
      #pragma unroll
      for (int kt = 0; kt < 4; ++kt)
        xfrag[kt] = pack8(xr0[kt], xr1[kt]);
    }

    #pragma unroll
    for (int ct = 0; ct < 2; ++ct) {
      int col = w * 32 + ct * 16 + l15;
      #pragma unroll
      for (int q = 0; q < 4; ++q) {
        int row = lk * 4 + q;
        float ht = fast_tanh(acc2[ct][q]);
        float ho = hreg[ct][q];
        float hn = __builtin_fmaf(zp[ct][q], ht - ho, ho);
        hreg[ct][q] = hn;
        __bf16 hb = (__bf16)hn;
        lds_a[row * LDA_STRIDE + col] = __builtin_bit_cast(short, hb);
      }
    }
    barrier_lds();
  }

  #pragma unroll
  for (int ct = 0; ct < 2; ++ct) {
    int col = w * 32 + ct * 16 + l15;
    #pragma unroll
    for (int q = 0; q < 4; ++q) {
      int row = lk * 4 + q;
      out[(size_t)(r0 + row) * H_DIM + col] = hreg[ct][q];
    }
  }
}

extern "C" void kernel_launch(void* const* d_in, const int* in_sizes, int n_in,
                              void* d_out, int out_size, void* d_ws, size_t ws_size,
                              hipStream_t stream) {
  (void)in_sizes; (void)n_in; (void)out_size;
  const float* inputs = (const float*)d_in[0];
  const float* attn   = (const float*)d_in[1];
  const float* Wz     = (const float*)d_in[2];
  const float* bz     = (const float*)d_in[3];
  const float* Wr     = (const float*)d_in[4];
  const float* br     = (const float*)d_in[5];
  const float* Wh     = (const float*)d_in[6];
  const float* bh     = (const float*)d_in[7];
  float* out = (float*)d_out;

  if (ws_size >= PRE_BYTES) {
    char* pre = (char*)d_ws;
    xproj_kernel<<<NBLK * (T_N / TCHUNK), 256, 0, stream>>>(inputs, Wz, bz, Wr, br, Wh, bh, pre);
    augru_rec_kernel<<<32, 1024, 0, stream>>>(pre, attn, Wz, Wr, Wh, out);
  } else {
    augru_kernel<<<NBLK, 256, 0, stream>>>(inputs, attn, Wz, bz, Wr, br, Wh, bh, out);
  }
}

// Round 18
// 225.607 us; speedup vs baseline: 9.6239x; 1.9481x over previous
//
#include <hip/hip_runtime.h>

// AUGRU, round 18: REVERT to R15 (best verified: 225.5 us).
//  Pass 1 (xproj): coop-LDS-staged, coalesced both sides (~56 us).
//  Pass 2 (rec): 64 blocks x 8 waves; frag-major conflict-free LDS for h/rh;
//     preacts ring depth 2; 2 raw barriers/step (~169 us).
//  R16/R17 phase-offset attempts both died on VGPR spill (WRITE_SIZE 1664KB);
//  reverting per pre-commit.
// Fallback: proven single-kernel (R2) if ws too small.

#define T_N   200
#define I_DIM 128
#define H_DIM 128
#define NBLK  64
#define TCHUNK 25

typedef float  f32x4  __attribute__((ext_vector_type(4)));
typedef __bf16 bf16x4 __attribute__((ext_vector_type(4)));
typedef __bf16 bf16x8 __attribute__((ext_vector_type(8)));

// preact layout: ((t*NBLK+bblk)*3 + g)*4096 + hidgrp*128 + b*8
#define GATE_BYTES 4096
#define PB_BYTES   (3 * GATE_BYTES)
#define PRE_BYTES  ((size_t)T_N * NBLK * PB_BYTES)   // 157,286,400

// fallback LDS
#define LDA_STRIDE 264
#define LATT_STRIDE 201

__device__ __forceinline__ float fast_sigmoid(float x) {
  float e = __builtin_amdgcn_exp2f(-1.4426950408889634f * x);
  return __builtin_amdgcn_rcpf(1.0f + e);
}
__device__ __forceinline__ float fast_tanh(float x) {
  float e = __builtin_amdgcn_exp2f(2.8853900817779268f * x);
  return 1.0f - 2.0f * __builtin_amdgcn_rcpf(1.0f + e);
}
__device__ __forceinline__ void barrier_lds() {
  asm volatile("s_waitcnt lgkmcnt(0)\n\ts_barrier" ::: "memory");
}
__device__ __forceinline__ bf16x8 pack8(float4 a, float4 b) {
  bf16x8 t;
  t[0] = (__bf16)a.x; t[1] = (__bf16)a.y; t[2] = (__bf16)a.z; t[3] = (__bf16)a.w;
  t[4] = (__bf16)b.x; t[5] = (__bf16)b.y; t[6] = (__bf16)b.z; t[7] = (__bf16)b.w;
  return t;
}
// XOR-swizzled byte offset within a [16 row][256 B] bf16 LDS tile (xproj only)
__device__ __forceinline__ int swz(int row, int bytecol) {
  return row * 256 + (bytecol ^ ((row & 7) << 4));
}

// ---------------------------------------------------------------------------
// Pass 1: x-projections, coop-LDS-staged. grid = 64 bblk * 8 tchunks, 256 thr.
// ---------------------------------------------------------------------------
__global__ __launch_bounds__(256, 2)
void xproj_kernel(const float* __restrict__ inputs,
                  const float* __restrict__ Wz, const float* __restrict__ bz,
                  const float* __restrict__ Wr, const float* __restrict__ br,
                  const float* __restrict__ Wh, const float* __restrict__ bh,
                  char* __restrict__ pre) {
  __shared__ __align__(16) char lds_x[2 * 4096];

  const int tid  = threadIdx.x;
  const int w    = tid >> 6;
  const int l    = tid & 63;
  const int l15  = l & 15;
  const int lk   = l >> 4;
  const int bblk = blockIdx.x & (NBLK - 1);
  const int t0   = (blockIdx.x >> 6) * TCHUNK;
  const int r0   = bblk * 16;

  const int crow  = tid >> 4;
  const int cslot = tid & 15;
  const float* xsrc = inputs + (size_t)(r0 + crow) * (T_N * I_DIM) + cslot * 8;
  const int cwoff = swz(crow, cslot * 16);

  bf16x8 wb[24];
  f32x4  bias4[6];
  #pragma unroll
  for (int s = 0; s < 6; ++s) {
    int hid0 = w * 32 + (s & 1) * 16;
    const float* Wp; const float* bp;
    if (s < 2)      { Wp = Wz; bp = bz; }
    else if (s < 4) { Wp = Wr; bp = br; }
    else            { Wp = Wh; bp = bh; }
    float4 bv = *(const float4*)&bp[hid0 + lk * 4];
    bias4[s][0] = bv.x; bias4[s][1] = bv.y; bias4[s][2] = bv.z; bias4[s][3] = bv.w;
    const float* Wrow = Wp + (size_t)(hid0 + l15) * 256;
    #pragma unroll
    for (int kt = 0; kt < 4; ++kt) {
      const float* p = Wrow + kt * 32 + lk * 8;
      wb[s * 4 + kt] = pack8(*(const float4*)p, *(const float4*)(p + 4));
    }
  }

  {
    const float* p = xsrc + (size_t)t0 * I_DIM;
    float4 a = *(const float4*)p;
    float4 b = *(const float4*)(p + 4);
    *(bf16x8*)(lds_x + cwoff) = pack8(a, b);
  }
  barrier_lds();

  #pragma unroll 2
  for (int ti = 0; ti < TCHUNK; ++ti) {
    const int t = t0 + ti;
    float4 ra, rb2;
    if (ti + 1 < TCHUNK) {
      const float* p = xsrc + (size_t)(t + 1) * I_DIM;
      ra  = *(const float4*)p;
      rb2 = *(const float4*)(p + 4);
    }

    char* bufc = lds_x + ((ti & 1) ? 4096 : 0);
    bf16x8 xf[4];
    #pragma unroll
    for (int kt = 0; kt < 4; ++kt)
      xf[kt] = *(const bf16x8*)(bufc + swz(l15, kt * 64 + lk * 16));

    f32x4 acc[6];
    #pragma unroll
    for (int s = 0; s < 6; ++s) acc[s] = bias4[s];
    #pragma unroll
    for (int kt = 0; kt < 4; ++kt)
      #pragma unroll
      for (int s = 0; s < 6; ++s)
        acc[s] = __builtin_amdgcn_mfma_f32_16x16x32_bf16(wb[s * 4 + kt], xf[kt], acc[s], 0, 0, 0);

    char* base = pre + ((size_t)t * NBLK + bblk) * PB_BYTES;
    #pragma unroll
    for (int s = 0; s < 6; ++s) {
      int g      = s >> 1;
      int hidgrp = w * 8 + (s & 1) * 4 + lk;
      bf16x4 v;
      v[0] = (__bf16)acc[s][0]; v[1] = (__bf16)acc[s][1];
      v[2] = (__bf16)acc[s][2]; v[3] = (__bf16)acc[s][3];
      *(bf16x4*)(base + g * GATE_BYTES + hidgrp * 128 + l15 * 8) = v;
    }

    if (ti + 1 < TCHUNK) {
      char* bufn = lds_x + (((ti + 1) & 1) ? 4096 : 0);
      *(bf16x8*)(bufn + cwoff) = pack8(ra, rb2);
    }
    barrier_lds();
  }
}

// ---------------------------------------------------------------------------
// Pass 2: recurrence, 64 blocks x 8 waves, fragment-major LDS.
// ---------------------------------------------------------------------------
__global__ __launch_bounds__(512, 1)
void augru_rec_kernel(const char* __restrict__ pre,
                      const float* __restrict__ attn,
                      const float* __restrict__ Wz,
                      const float* __restrict__ Wr,
                      const float* __restrict__ Wh,
                      float* __restrict__ out) {
  __shared__ __align__(16) char lds_h [4096];   // frag-major bf16 h
  __shared__ __align__(16) char lds_rh[4096];   // frag-major bf16 rh
  __shared__ float lds_att[T_N * 16];           // [t][batch]

  const int tid   = threadIdx.x;
  const int w     = tid >> 6;
  const int l     = tid & 63;
  const int l15   = l & 15;          // batch lane
  const int lk    = l >> 4;
  const int r0    = blockIdx.x * 16;
  const int myhid = w * 16 + lk * 4;

  for (int idx = tid; idx < T_N * 16; idx += 512) {
    int t = idx >> 4, b = idx & 15;
    lds_att[idx] = attn[(size_t)(r0 + b) * T_N + t];
  }
  for (int idx = tid * 4; idx < 4096; idx += 512 * 4)
    *(float*)(lds_h + idx) = 0.0f;

  bf16x8 wzH[4], wrH[4], whH[4];
  {
    const float* pz = Wz + (size_t)(w * 16 + l15) * 256 + 128;
    const float* pr = Wr + (size_t)(w * 16 + l15) * 256 + 128;
    const float* ph = Wh + (size_t)(w * 16 + l15) * 256 + 128;
    #pragma unroll
    for (int kt = 0; kt < 4; ++kt) {
      const float* a = pz + kt * 32 + lk * 8;
      wzH[kt] = pack8(*(const float4*)a, *(const float4*)(a + 4));
      const float* b = pr + kt * 32 + lk * 8;
      wrH[kt] = pack8(*(const float4*)b, *(const float4*)(b + 4));
      const float* cc = ph + kt * 32 + lk * 8;
      whH[kt] = pack8(*(const float4*)cc, *(const float4*)(cc + 4));
    }
  }

  float hreg[4];
  #pragma unroll
  for (int q = 0; q < 4; ++q) hreg[q] = 0.0f;

  // preact ring (depth 2), strength-reduced pointer walk
  const char* pb = pre + (size_t)blockIdx.x * PB_BYTES + (w * 4 + lk) * 128 + l15 * 8;
  const size_t tstride = (size_t)NBLK * PB_BYTES;
  bf16x4 pf[2][3];
  #pragma unroll
  for (int d = 0; d < 2; ++d)
    #pragma unroll
    for (int g = 0; g < 3; ++g)
      pf[d][g] = *(const bf16x4*)(pb + d * tstride + g * GATE_BYTES);
  const char* pnx = pb + 2 * tstride;   // prefetch pointer for t+2

  // frag-major offsets:
  // read  (per kt): kt*1024 + (lk*16 + l15)*16
  // write (one b64): (w>>1)*1024 + (((w&1)*2 + (lk>>1))*16 + l15)*16 + (lk&1)*8
  const int rd_base = (lk * 16 + l15) * 16;
  const int wr_off  = (w >> 1) * 1024 + ((((w & 1) * 2) + (lk >> 1)) * 16 + l15) * 16 + (lk & 1) * 8;

  __syncthreads();

  #pragma unroll 2
  for (int t = 0; t < T_N; ++t) {
    float pzv[4], prv[4], phv[4];
    #pragma unroll
    for (int q = 0; q < 4; ++q) {
      pzv[q] = (float)pf[t & 1][0][q];
      prv[q] = (float)pf[t & 1][1][q];
      phv[q] = (float)pf[t & 1][2][q];
    }
    if (t + 2 < T_N) {
      #pragma unroll
      for (int g = 0; g < 3; ++g)
        pf[t & 1][g] = *(const bf16x4*)(pnx + g * GATE_BYTES);
      pnx += tstride;
    }

    bf16x8 hb[4];
    #pragma unroll
    for (int kt = 0; kt < 4; ++kt)
      hb[kt] = *(const bf16x8*)(lds_h + kt * 1024 + rd_base);
    const float av = lds_att[t * 16 + l15];

    f32x4 zA, zB, rA, rB;
    { f32x4 a; a[0]=pzv[0]; a[1]=pzv[1]; a[2]=pzv[2]; a[3]=pzv[3]; zA = a; }
    { f32x4 a; a[0]=prv[0]; a[1]=prv[1]; a[2]=prv[2]; a[3]=prv[3]; rA = a; }
    { f32x4 z; z[0]=0.f; z[1]=0.f; z[2]=0.f; z[3]=0.f; zB = z; rB = z; }
    zA = __builtin_amdgcn_mfma_f32_16x16x32_bf16(wzH[0], hb[0], zA, 0, 0, 0);
    rA = __builtin_amdgcn_mfma_f32_16x16x32_bf16(wrH[0], hb[0], rA, 0, 0, 0);
    zB = __builtin_amdgcn_mfma_f32_16x16x32_bf16(wzH[1], hb[1], zB, 0, 0, 0);
    rB = __builtin_amdgcn_mfma_f32_16x16x32_bf16(wrH[1], hb[1], rB, 0, 0, 0);
    zA = __builtin_amdgcn_mfma_f32_16x16x32_bf16(wzH[2], hb[2], zA, 0, 0, 0);
    rA = __builtin_amdgcn_mfma_f32_16x16x32_bf16(wrH[2], hb[2], rA, 0, 0, 0);
    zB = __builtin_amdgcn_mfma_f32_16x16x32_bf16(wzH[3], hb[3], zB, 0, 0, 0);
    rB = __builtin_amdgcn_mfma_f32_16x16x32_bf16(wrH[3], hb[3], rB, 0, 0, 0);

    bf16x4 rhv;
    #pragma unroll
    for (int q = 0; q < 4; ++q) {
      float rr = fast_sigmoid(rA[q] + rB[q]);
      rhv[q] = (__bf16)(rr * hreg[q]);
    }
    *(bf16x4*)(lds_rh + wr_off) = rhv;
    float zp[4];
    #pragma unroll
    for (int q = 0; q < 4; ++q)
      zp[q] = av * fast_sigmoid(zA[q] + zB[q]);
    barrier_lds();  // B1: rh visible

    bf16x8 rb[4];
    #pragma unroll
    for (int kt = 0; kt < 4; ++kt)
      rb[kt] = *(const bf16x8*)(lds_rh + kt * 1024 + rd_base);
    f32x4 hA, hB;
    { f32x4 a; a[0]=phv[0]; a[1]=phv[1]; a[2]=phv[2]; a[3]=phv[3]; hA = a; }
    { f32x4 z; z[0]=0.f; z[1]=0.f; z[2]=0.f; z[3]=0.f; hB = z; }
    hA = __builtin_amdgcn_mfma_f32_16x16x32_bf16(whH[0], rb[0], hA, 0, 0, 0);
    hB = __builtin_amdgcn_mfma_f32_16x16x32_bf16(whH[1], rb[1], hB, 0, 0, 0);
    hA = __builtin_amdgcn_mfma_f32_16x16x32_bf16(whH[2], rb[2], hA, 0, 0, 0);
    hB = __builtin_amdgcn_mfma_f32_16x16x32_bf16(whH[3], rb[3], hB, 0, 0, 0);

    bf16x4 hbv;
    #pragma unroll
    for (int q = 0; q < 4; ++q) {
      float ht = fast_tanh(hA[q] + hB[q]);
      float hn = __builtin_fmaf(zp[q], ht - hreg[q], hreg[q]);
      hreg[q] = hn;
      hbv[q] = (__bf16)hn;
    }
    *(bf16x4*)(lds_h + wr_off) = hbv;
    barrier_lds();  // B2: h visible
  }

  float4 o;
  o.x = hreg[0]; o.y = hreg[1]; o.z = hreg[2]; o.w = hreg[3];
  *(float4*)&out[(size_t)(r0 + l15) * H_DIM + myhid] = o;
}

// ---------------------------------------------------------------------------
// Fallback: proven single-kernel version (round 2, 410 us).
// ---------------------------------------------------------------------------
__global__ __launch_bounds__(256, 1)
void augru_kernel(const float* __restrict__ inputs,
                  const float* __restrict__ attn,
                  const float* __restrict__ Wz, const float* __restrict__ bz,
                  const float* __restrict__ Wr, const float* __restrict__ br,
                  const float* __restrict__ Wh, const float* __restrict__ bh,
                  float* __restrict__ out) {
  __shared__ __align__(16) short lds_a[16 * LDA_STRIDE];
  __shared__ float lds_att[16 * LATT_STRIDE];

  const int tid = threadIdx.x;
  const int w   = tid >> 6;
  const int l   = tid & 63;
  const int l15 = l & 15;
  const int lk  = l >> 4;
  const int r0  = blockIdx.x * 16;

  for (int idx = tid; idx < 16 * T_N; idx += 256) {
    int row = idx / T_N, t = idx - row * T_N;
    lds_att[row * LATT_STRIDE + t] = attn[(size_t)(r0 + row) * T_N + t];
  }
  for (int idx = tid; idx < 16 * H_DIM; idx += 256) {
    int row = idx >> 7, c = idx & 127;
    lds_a[row * LDA_STRIDE + c] = 0;
  }

  bf16x8 w1[32];
  float  bias1[4];
  #pragma unroll
  for (int ct = 0; ct < 4; ++ct) {
    int n = w * 32 + (ct & 1) * 16 + l15;
    const float* Wp; float bv;
    if (ct < 2) { Wp = Wz + (size_t)n * 256; bv = bz[n]; }
    else        { Wp = Wr + (size_t)n * 256; bv = br[n]; }
    bias1[ct] = bv;
    #pragma unroll
    for (int kt = 0; kt < 8; ++kt) {
      const float* p = Wp + kt * 32 + lk * 8;
      w1[ct * 8 + kt] = pack8(*(const float4*)p, *(const float4*)(p + 4));
    }
  }
  bf16x8 w2[16];
  float  bias2[2];
  #pragma unroll
  for (int ct = 0; ct < 2; ++ct) {
    int n = w * 32 + ct * 16 + l15;
    bias2[ct] = bh[n];
    const float* Wp = Wh + (size_t)n * 256;
    #pragma unroll
    for (int kt = 0; kt < 8; ++kt) {
      const float* p = Wp + kt * 32 + lk * 8;
      w2[ct * 8 + kt] = pack8(*(const float4*)p, *(const float4*)(p + 4));
    }
  }

  float hreg[2][4];
  #pragma unroll
  for (int ct = 0; ct < 2; ++ct)
    #pragma unroll
    for (int q = 0; q < 4; ++q) hreg[ct][q] = 0.0f;

  const float* xbase = inputs + (size_t)(r0 + l15) * (T_N * I_DIM);
  bf16x8 xfrag[4];
  #pragma unroll
  for (int kt = 0; kt < 4; ++kt) {
    const float* p = xbase + kt * 32 + lk * 8;
    xfrag[kt] = pack8(*(const float4*)p, *(const float4*)(p + 4));
  }

  __syncthreads();

  float4 xr0[4], xr1[4];
  for (int t = 0; t < T_N; ++t) {
    if (t + 1 < T_N) {
      #pragma unroll
      for (int kt = 0; kt < 4; ++kt) {
        const float* p = xbase + (size_t)(t + 1) * I_DIM + kt * 32 + lk * 8;
        xr0[kt] = *(const float4*)p;
        xr1[kt] = *(const float4*)(p + 4);
      }
    }
    bf16x8 hfrag[4];
    #pragma unroll
    for (int kt = 0; kt < 4; ++kt)
      hfrag[kt] = *(const bf16x8*)&lds_a[l15 * LDA_STRIDE + kt * 32 + lk * 8];
    float av[4];
    #pragma unroll
    for (int q = 0; q < 4; ++q) av[q] = lds_att[(lk * 4 + q) * LATT_STRIDE + t];

    f32x4 acc[4];
    #pragma unroll
    for (int ct = 0; ct < 4; ++ct) {
      f32x4 a; a[0] = bias1[ct]; a[1] = bias1[ct]; a[2] = bias1[ct]; a[3] = bias1[ct];
      acc[ct] = a;
    }
    #pragma unroll
    for (int kt = 0; kt < 4; ++kt)
      #pragma unroll
      for (int ct = 0; ct < 4; ++ct)
        acc[ct] = __builtin_amdgcn_mfma_f32_16x16x32_bf16(xfrag[kt], w1[ct * 8 + kt], acc[ct], 0, 0, 0);

    f32x4 acc2[2];
    #pragma unroll
    for (int ct = 0; ct < 2; ++ct) {
      f32x4 a; a[0] = bias2[ct]; a[1] = bias2[ct]; a[2] = bias2[ct]; a[3] = bias2[ct];
      acc2[ct] = a;
    }
    #pragma unroll
    for (int kt = 0; kt < 4; ++kt)
      #pragma unroll
      for (int ct = 0; ct < 2; ++ct)
        acc2[ct] = __builtin_amdgcn_mfma_f32_16x16x32_bf16(xfrag[kt], w2[ct * 8 + kt], acc2[ct], 0, 0, 0);

    #pragma unroll
    for (int kt = 0; kt < 4; ++kt)
      #pragma unroll
      for (int ct = 0; ct < 4; ++ct)
        acc[ct] = __builtin_amdgcn_mfma_f32_16x16x32_bf16(hfrag[kt], w1[ct * 8 + 4 + kt], acc[ct], 0, 0, 0);

    float zp[2][4];
    #pragma unroll
    for (int ct = 0; ct < 2; ++ct) {
      int col = w * 32 + ct * 16 + l15;
      #pragma unroll
      for (int q = 0; q < 4; ++q) {
        int row = lk * 4 + q;
        zp[ct][q] = av[q] * fast_sigmoid(acc[ct][q]);
        float rr = fast_sigmoid(acc[2 + ct][q]);
        __bf16 rhb = (__bf16)(rr * hreg[ct][q]);
        lds_a[row * LDA_STRIDE + 128 + col] = __builtin_bit_cast(short, rhb);
      }
    }
    barrier_lds();

    bf16x8 rfrag[4];
    #pragma unroll
    for (int kt = 0; kt < 4; ++kt)
      rfrag[kt] = *(const bf16x8*)&lds_a[l15 * LDA_STRIDE + 128 + kt * 32 + lk * 8];
    #pragma unroll
    for (int kt = 0; kt < 4; ++kt)
      #pragma unroll
      for (int ct = 0; ct < 2; ++ct)
        acc2[ct] = __builtin_amdgcn_mfma_f32_16x16x32_bf16(rfrag[kt], w2[ct * 8 + 4 + kt], acc2[ct], 0, 0, 0);

    if (t + 1 < T_N) {
      #pragma unroll
      for (int kt = 0; kt < 4; ++kt)
        xfrag[kt] = pack8(xr0[kt], xr1[kt]);
    }

    #pragma unroll
    for (int ct = 0; ct < 2; ++ct) {
      int col = w * 32 + ct * 16 + l15;
      #pragma unroll
      for (int q = 0; q < 4; ++q) {
        int row = lk * 4 + q;
        float ht = fast_tanh(acc2[ct][q]);
        float ho = hreg[ct][q];
        float hn = __builtin_fmaf(zp[ct][q], ht - ho, ho);
        hreg[ct][q] = hn;
        __bf16 hb = (__bf16)hn;
        lds_a[row * LDA_STRIDE + col] = __builtin_bit_cast(short, hb);
      }
    }
    barrier_lds();
  }

  #pragma unroll
  for (int ct = 0; ct < 2; ++ct) {
    int col = w * 32 + ct * 16 + l15;
    #pragma unroll
    for (int q = 0; q < 4; ++q) {
      int row = lk * 4 + q;
      out[(size_t)(r0 + row) * H_DIM + col] = hreg[ct][q];
    }
  }
}

extern "C" void kernel_launch(void* const* d_in, const int* in_sizes, int n_in,
                              void* d_out, int out_size, void* d_ws, size_t ws_size,
                              hipStream_t stream) {
  (void)in_sizes; (void)n_in; (void)out_size;
  const float* inputs = (const float*)d_in[0];
  const float* attn   = (const float*)d_in[1];
  const float* Wz     = (const float*)d_in[2];
  const float* bz     = (const float*)d_in[3];
  const float* Wr     = (const float*)d_in[4];
  const float* br     = (const float*)d_in[5];
  const float* Wh     = (const float*)d_in[6];
  const float* bh     = (const float*)d_in[7];
  float* out = (float*)d_out;

  if (ws_size >= PRE_BYTES) {
    char* pre = (char*)d_ws;
    xproj_kernel<<<NBLK * (T_N / TCHUNK), 256, 0, stream>>>(inputs, Wz, bz, Wr, br, Wh, bh, pre);
    augru_rec_kernel<<<NBLK, 512, 0, stream>>>(pre, attn, Wz, Wr, Wh, out);
  } else {
    augru_kernel<<<NBLK, 256, 0, stream>>>(inputs, attn, Wz, bz, Wr, br, Wh, bh, out);
  }
}